// Round 6
// baseline (547.569 us; speedup 1.0000x reference)
//
#include <hip/hip_runtime.h>
#include <cstdint>
#include <cstddef>

// Problem: B=1, S=2048, H=4096, NH=32, NKV=8, D=128, rope theta 1e4, causal GQA attn.
// Inputs f32: hidden[2048][4096], w_qkv[4096][6144], w_o[4096][4096], mask(tril, unused), pos(arange, unused)
// Output f32 [2048][4096]
// R6: GEMMs -> 256^2 tile, 8 waves, 3-deep LDS ring, 1 raw barrier/K-step, counted vmcnt(4) (T3/T4 essence).

#define DEV __device__ __forceinline__

typedef __attribute__((ext_vector_type(4))) float  f32x4;
typedef __attribute__((ext_vector_type(4))) short  short4v;
typedef __attribute__((ext_vector_type(8))) short  short8;
typedef __attribute__((ext_vector_type(8))) __bf16 bf16x8;

DEV short f32_to_bf16(float x) {
  union { float f; uint32_t u; } v; v.f = x;
  uint32_t r = v.u + 0x7fffu + ((v.u >> 16) & 1u);   // RNE
  return (short)(r >> 16);
}

union frag_u { short4v h[2]; bf16x8 v; short s[8]; };
DEV bf16x8 comb(short4v lo, short4v hi) { frag_u u; u.h[0] = lo; u.h[1] = hi; return u.v; }

DEV f32x4 MFMA(bf16x8 a, bf16x8 b, f32x4 c) {
  return __builtin_amdgcn_mfma_f32_16x16x32_bf16(a, b, c, 0, 0, 0);
}

typedef __attribute__((address_space(1))) void* gas1p;
typedef __attribute__((address_space(3))) void* as3p;
DEV void gld16(const void* g, void* l) {
  // async global->LDS, 16B/lane; LDS dest = wave-uniform base + lane*16
  __builtin_amdgcn_global_load_lds((gas1p)g, (as3p)l, 16, 0, 0);
}

// ---------------- prep kernels ----------------

__global__ __launch_bounds__(256) void k_cvt_bf16(const float* __restrict__ x,
                                                  short* __restrict__ y, int n4) {
  int i = blockIdx.x * 256 + threadIdx.x;
  int stride = gridDim.x * 256;
  for (; i < n4; i += stride) {
    f32x4 v = ((const f32x4*)x)[i];
    short4v o;
    o[0] = f32_to_bf16(v[0]); o[1] = f32_to_bf16(v[1]);
    o[2] = f32_to_bf16(v[2]); o[3] = f32_to_bf16(v[3]);
    ((short4v*)y)[i] = o;
  }
}

// dst[c][r] = bf16(src[r][c]);  src is [R][C] f32
__global__ __launch_bounds__(256) void k_transpose_bf16(const float* __restrict__ src,
                                                        short* __restrict__ dst, int R, int C) {
  __shared__ float tile[32][33];
  const int c0 = blockIdx.x * 32, r0 = blockIdx.y * 32;
  const int tx = threadIdx.x & 31, ty = threadIdx.x >> 5;
  #pragma unroll
  for (int i = ty; i < 32; i += 8) tile[i][tx] = src[(long)(r0 + i) * C + c0 + tx];
  __syncthreads();
  #pragma unroll
  for (int i = ty; i < 32; i += 8) dst[(long)(c0 + i) * R + r0 + tx] = f32_to_bf16(tile[tx][i]);
}

__global__ void k_rope_tab(float* __restrict__ ct, float* __restrict__ st) {
  const int s = blockIdx.x, j = threadIdx.x;   // grid 2048 x 64
  float inv = powf(10000.0f, -(float)j * (1.0f / 64.0f));
  float a = (float)s * inv;
  ct[s * 64 + j] = cosf(a);
  st[s * 64 + j] = sinf(a);
}

// From C1[s][6144] f32: rope+pack Q->Qh[32][2048][128], K->Kh[8][2048][128], V->Vt[8][128][2048] (transposed)
__global__ __launch_bounds__(256) void k_rope_pack(const float* __restrict__ C1,
                                                   const float* __restrict__ ct,
                                                   const float* __restrict__ st,
                                                   short* __restrict__ Qh,
                                                   short* __restrict__ Kh,
                                                   short* __restrict__ Vt) {
  const int s = blockIdx.x, t = threadIdx.x;
  const float* row = C1 + (long)s * 6144;
  const float* cr = ct + s * 64;
  const float* sr = st + s * 64;
  for (int i = t; i < 2048; i += 256) {       // Q: 32 heads * 64 pairs
    int hh = i >> 6, j = i & 63;
    float c = cr[j], sn = sr[j];
    float x0 = row[hh * 128 + j], x1 = row[hh * 128 + j + 64];
    long o = ((long)hh * 2048 + s) * 128 + j;
    Qh[o]      = f32_to_bf16(x0 * c - x1 * sn);
    Qh[o + 64] = f32_to_bf16(x1 * c + x0 * sn);
  }
  for (int i = t; i < 512; i += 256) {        // K: 8 heads * 64 pairs
    int hh = i >> 6, j = i & 63;
    float c = cr[j], sn = sr[j];
    float x0 = row[4096 + hh * 128 + j], x1 = row[4096 + hh * 128 + j + 64];
    long o = ((long)hh * 2048 + s) * 128 + j;
    Kh[o]      = f32_to_bf16(x0 * c - x1 * sn);
    Kh[o + 64] = f32_to_bf16(x1 * c + x0 * sn);
  }
  for (int i = t; i < 1024; i += 256) {       // V transpose: Vt[h][d][s]
    int hh = i >> 7, d = i & 127;
    Vt[((long)hh * 128 + d) * 2048 + s] = f32_to_bf16(row[5120 + i]);
  }
}

// ---------------- GEMM: C[M][N] = A[M][K] * B^T   (Bt is [N][K] bf16) ----------------
// 256x256 tile, BK=32, 8 waves (2Mx4N), 3-deep LDS ring, counted vmcnt(4), raw barriers.
// Ring invariant at tile t: buf[t%3]=t (resident), buf[(t+1)%3]=t+1 (landed by vmcnt at end of t-1),
// buf[(t+2)%3]=free (t-1's reads done at its end barrier) -> stage t+2 there.

template<int OUT_BF16>
__global__ __launch_bounds__(512, 2) void k_gemm_bt(const short* __restrict__ A,
                                                    const short* __restrict__ Bt,
                                                    void* __restrict__ Cp,
                                                    int M, int N, int K) {
  __shared__ short As[3][256 * 32];
  __shared__ short Bs[3][256 * 32];    // 96 KiB total
  const int tid = threadIdx.x;
  const int lane = tid & 63;
  const int w = tid >> 6;              // 0..7
  const int wr = (w >> 2) * 128;       // wave M-offset
  const int wc = (w & 3) * 64;         // wave N-offset
  const int g = lane >> 4, r16 = lane & 15;
  const long m0 = (long)blockIdx.y * 256;
  const long n0 = (long)blockIdx.x * 256;

  const int sr = lane >> 2;            // staging row within 16-row slab
  const int scb = (lane & 3) * 8;      // staging col (elements)

  f32x4 acc[8][4] = {};
  const int NT = K >> 5;               // K/32 tiles

  // stage tile t into ring buffer b: 4 gld16/thread (A x2 slabs, B x2 slabs)
  #define STAGE(t, b)                                                              \
    {                                                                              \
      const long k0 = (long)(t) << 5;                                              \
      _Pragma("unroll")                                                            \
      for (int iss = 0; iss < 2; ++iss) {                                          \
        const int slab = w * 2 + iss;            /* 0..15 */                       \
        const int row = slab * 16 + sr;                                            \
        gld16(A  + (m0 + row) * K + k0 + scb, (char*)As[b] + slab * 1024);         \
        gld16(Bt + (n0 + row) * K + k0 + scb, (char*)Bs[b] + slab * 1024);         \
      }                                                                            \
    }

  // prologue: tiles 0,1
  STAGE(0, 0);
  STAGE(1, 1);
  asm volatile("s_waitcnt vmcnt(4)" ::: "memory");   // tile 0 landed
  __builtin_amdgcn_s_barrier();
  __builtin_amdgcn_sched_barrier(0);

  int cur = 0;
  for (int t = 0; t < NT; ++t) {
    const int nb = cur + 2 - ((cur + 2 >= 3) ? 3 : 0);   // (cur+2)%3
    if (t + 2 < NT) STAGE(t + 2, nb);

    bf16x8 af[8], bfv[4];
    const short* Ab = As[cur];
    const short* Bb = Bs[cur];
    #pragma unroll
    for (int m = 0; m < 8; ++m) af[m]  = *(const bf16x8*)(Ab + (wr + m * 16 + r16) * 32 + g * 8);
    #pragma unroll
    for (int n = 0; n < 4; ++n) bfv[n] = *(const bf16x8*)(Bb + (wc + n * 16 + r16) * 32 + g * 8);
    asm volatile("s_waitcnt lgkmcnt(0)" ::: "memory");
    __builtin_amdgcn_sched_barrier(0);

    __builtin_amdgcn_s_setprio(1);
    #pragma unroll
    for (int m = 0; m < 8; ++m)
      #pragma unroll
      for (int n = 0; n < 4; ++n)
        acc[m][n] = MFMA(af[m], bfv[n], acc[m][n]);
    __builtin_amdgcn_s_setprio(0);
    __builtin_amdgcn_sched_barrier(0);

    if (t + 2 < NT) { asm volatile("s_waitcnt vmcnt(4)" ::: "memory"); }  // tile t+1 landed, t+2 in flight
    else            { asm volatile("s_waitcnt vmcnt(0)" ::: "memory"); }  // tail drain
    __builtin_amdgcn_s_barrier();
    __builtin_amdgcn_sched_barrier(0);

    cur = cur + 1 - ((cur + 1 >= 3) ? 3 : 0);
  }
  #undef STAGE

  #pragma unroll
  for (int m = 0; m < 8; ++m) {
    #pragma unroll
    for (int n = 0; n < 4; ++n) {
      const long col = n0 + wc + n * 16 + r16;
      #pragma unroll
      for (int j = 0; j < 4; ++j) {
        const long row = m0 + wr + m * 16 + g * 4 + j;   // C/D: col=lane&15, row=(lane>>4)*4+reg
        if (OUT_BF16) ((short*)Cp)[row * N + col] = f32_to_bf16(acc[m][n][j]);
        else          ((float*)Cp)[row * N + col] = acc[m][n][j];
      }
    }
  }
}

// ---------------- flash attention (causal, GQA 4:1), swapped-QK^T ----------------
// grid (h, qt) for CU load balance; reg-prefetch of next K/V tile (T14); setprio on MFMA (T5).

__global__ __launch_bounds__(256) void k_attn(const short* __restrict__ Qh,
                                              const short* __restrict__ Kh,
                                              const short* __restrict__ Vt,
                                              short* __restrict__ O) {
  __shared__ short Kl[64][136];   // 128 data + 8 pad shorts
  __shared__ short Vl[128][72];   // 64 data + 8 pad shorts
  const int h = blockIdx.x, qt = blockIdx.y, hk = h >> 2;   // x=h: balances qt across CUs
  const int tid = threadIdx.x, lane = tid & 63, w = tid >> 6;
  const int g = lane >> 4, r16 = lane & 15;
  const int q0 = qt * 64 + w * 16;
  const int q_glob = q0 + r16;

  // Q fragments (B-operand of swapped QK^T): col=q=lane&15, two-block k-slots over d
  bf16x8 qf[4];
  {
    const short* qb = Qh + ((long)h * 2048 + q0 + r16) * 128;
    #pragma unroll
    for (int c = 0; c < 4; ++c) {
      short4v lo = *(const short4v*)(qb + 32 * c + 4 * g);
      short4v hi = *(const short4v*)(qb + 32 * c + 16 + 4 * g);
      qf[c] = comb(lo, hi);
    }
  }
  const short* Kg = Kh + (long)hk * (2048 * 128);
  const short* Vg = Vt + (long)hk * (128 * 2048);

  f32x4 accO[8] = {};
  float mrun = -1e30f, lrun = 0.0f;

  // prefetch tile 0 into registers
  short8 kpre[4], vpre[4];
  #pragma unroll
  for (int j = 0; j < 4; ++j) {
    const int n = tid + j * 256;
    kpre[j] = *(const short8*)(Kg + ((long)(n >> 4)) * 128 + (n & 15) * 8);
    vpre[j] = *(const short8*)(Vg + (long)(n >> 3) * 2048 + (n & 7) * 8);
  }

  for (int kt = 0; kt <= qt; ++kt) {
    // write prefetched tile to LDS
    #pragma unroll
    for (int j = 0; j < 4; ++j) {
      const int n = tid + j * 256;
      *(short8*)(&Kl[n >> 4][(n & 15) * 8]) = kpre[j];
      *(short8*)(&Vl[n >> 3][(n & 7) * 8]) = vpre[j];
    }
    __syncthreads();

    // issue next tile's global loads now; HBM latency hides under QK+softmax+PV
    if (kt < qt) {
      const long koff = (long)(kt + 1) * 64;
      #pragma unroll
      for (int j = 0; j < 4; ++j) {
        const int n = tid + j * 256;
        kpre[j] = *(const short8*)(Kg + (koff + (n >> 4)) * 128 + (n & 15) * 8);
        vpre[j] = *(const short8*)(Vg + (long)(n >> 3) * 2048 + koff + (n & 7) * 8);
      }
    }

    // S^T = K * Q^T  (A = K tile rows, B = Q^T)
    f32x4 accS[4] = {};
    __builtin_amdgcn_s_setprio(1);
    #pragma unroll
    for (int kvf = 0; kvf < 4; ++kvf) {
      const short* kr = &Kl[kvf * 16 + r16][0];
      #pragma unroll
      for (int c = 0; c < 4; ++c) {
        short4v lo = *(const short4v*)(kr + 32 * c + 4 * g);
        short4v hi = *(const short4v*)(kr + 32 * c + 16 + 4 * g);
        accS[kvf] = MFMA(comb(lo, hi), qf[c], accS[kvf]);
      }
    }
    __builtin_amdgcn_s_setprio(0);

    // online softmax; lane owns q = q0 + (lane&15); kv = kt*64 + kvf*16 + 4*g + r
    float sc[4][4];
    float mt = -1e30f;
    #pragma unroll
    for (int kvf = 0; kvf < 4; ++kvf)
      #pragma unroll
      for (int r = 0; r < 4; ++r) {
        float s = accS[kvf][r] * 0.08838834764831845f;   // 1/sqrt(128)
        const int kvg = kt * 64 + kvf * 16 + g * 4 + r;
        if (kvg > q_glob) s = -1e30f;                    // causal
        sc[kvf][r] = s;
        mt = fmaxf(mt, s);
      }
    mt = fmaxf(mt, __shfl_xor(mt, 16));
    mt = fmaxf(mt, __shfl_xor(mt, 32));
    const float mnew = fmaxf(mrun, mt);
    const float scale = __expf(mrun - mnew);
    float ps = 0.0f;
    #pragma unroll
    for (int kvf = 0; kvf < 4; ++kvf)
      #pragma unroll
      for (int r = 0; r < 4; ++r) {
        float p = __expf(sc[kvf][r] - mnew);
        sc[kvf][r] = p;
        ps += p;
      }
    ps += __shfl_xor(ps, 16);
    ps += __shfl_xor(ps, 32);
    lrun = lrun * scale + ps;
    mrun = mnew;

    // P^T regs -> PV B-operand directly (same two-block k-slot pattern as V A-frags)
    frag_u p0, p1;
    #pragma unroll
    for (int e = 0; e < 4; ++e) {
      p0.s[e]     = f32_to_bf16(sc[0][e]);
      p0.s[e + 4] = f32_to_bf16(sc[1][e]);
      p1.s[e]     = f32_to_bf16(sc[2][e]);
      p1.s[e + 4] = f32_to_bf16(sc[3][e]);
    }
    #pragma unroll
    for (int df = 0; df < 8; ++df)
      #pragma unroll
      for (int j = 0; j < 4; ++j) accO[df][j] *= scale;

    // O^T += V^T * P   (A = V^T rows = d, two-block kv slots)
    __builtin_amdgcn_s_setprio(1);
    #pragma unroll
    for (int df = 0; df < 8; ++df) {
      const short* vr = &Vl[df * 16 + r16][0];
      short4v a0 = *(const short4v*)(vr + 4 * g);
      short4v a1 = *(const short4v*)(vr + 16 + 4 * g);
      short4v a2 = *(const short4v*)(vr + 32 + 4 * g);
      short4v a3 = *(const short4v*)(vr + 48 + 4 * g);
      accO[df] = MFMA(comb(a0, a1), p0.v, accO[df]);
      accO[df] = MFMA(comb(a2, a3), p1.v, accO[df]);
    }
    __builtin_amdgcn_s_setprio(0);
    __syncthreads();
  }

  const float invl = 1.0f / lrun;
  #pragma unroll
  for (int df = 0; df < 8; ++df)
    #pragma unroll
    for (int j = 0; j < 4; ++j) {
      const int d = df * 16 + g * 4 + j;     // O^T C/D: col=q, row=d
      O[(long)q_glob * 4096 + h * 128 + d] = f32_to_bf16(accO[df][j] * invl);
    }
}

// ---------------- launch ----------------

extern "C" void kernel_launch(void* const* d_in, const int* in_sizes, int n_in,
                              void* d_out, int out_size, void* d_ws, size_t ws_size,
                              hipStream_t stream) {
  const float* hs   = (const float*)d_in[0];
  const float* wqkv = (const float*)d_in[1];
  const float* wo   = (const float*)d_in[2];
  // d_in[3] mask (tril) and d_in[4] position_ids (arange) are implied by construction.

  const size_t OFF_HSB = 0;                 // 16,777,216  (aliased by Qh later)
  const size_t OFF_W1T = 16777216;          // 50,331,648
  const size_t OFF_WOT = 67108864;          // 33,554,432
  const size_t OFF_C1  = 100663296;         // 50,331,648  (first 16.7MB aliased by attn-out)
  const size_t OFF_CT  = 150994944;         //    524,288
  const size_t OFF_ST  = 151519232;         //    524,288
  const size_t OFF_KH  = 152043520;         //  4,194,304
  const size_t OFF_VT  = 156237824;         //  4,194,304  -> end 160,432,128
  if (ws_size < 160432128u) return;

  char* ws = (char*)d_ws;
  short* hsb = (short*)(ws + OFF_HSB);
  short* W1T = (short*)(ws + OFF_W1T);
  short* WoT = (short*)(ws + OFF_WOT);
  float* C1  = (float*)(ws + OFF_C1);
  float* ct  = (float*)(ws + OFF_CT);
  float* st  = (float*)(ws + OFF_ST);
  short* Kh  = (short*)(ws + OFF_KH);
  short* Vt  = (short*)(ws + OFF_VT);
  short* Qh  = hsb;                 // reuse: hsb dead after gemm1
  short* AO  = (short*)(ws + OFF_C1);   // reuse: C1 dead after rope_pack

  k_cvt_bf16<<<2048, 256, 0, stream>>>(hs, hsb, 2048 * 4096 / 4);
  k_transpose_bf16<<<dim3(6144 / 32, 4096 / 32), 256, 0, stream>>>(wqkv, W1T, 4096, 6144);
  k_transpose_bf16<<<dim3(4096 / 32, 4096 / 32), 256, 0, stream>>>(wo, WoT, 4096, 4096);
  k_rope_tab<<<2048, 64, 0, stream>>>(ct, st);
  k_gemm_bt<0><<<dim3(24, 8), 512, 0, stream>>>(hsb, W1T, (void*)C1, 2048, 6144, 4096);
  k_rope_pack<<<2048, 256, 0, stream>>>(C1, ct, st, Qh, Kh, Vt);
  k_attn<<<dim3(32, 32), 256, 0, stream>>>(Qh, Kh, Vt, AO);   // x=h, y=qt
  k_gemm_bt<0><<<dim3(16, 8), 512, 0, stream>>>(AO, WoT, (void*)d_out, 2048, 4096, 4096);  // f32 out
}

// Round 7
// 449.512 us; speedup vs baseline: 1.2181x; 1.2181x over previous
//
#include <hip/hip_runtime.h>
#include <cstdint>
#include <cstddef>

// Problem: B=1, S=2048, H=4096, NH=32, NKV=8, D=128, rope theta 1e4, causal GQA attn.
// Inputs f32: hidden[2048][4096], w_qkv[4096][6144], w_o[4096][4096], mask(tril, unused), pos(arange, unused)
// Output f32 [2048][4096]
// R7: GEMMs -> m201-style 8-phase, BK=64, 2-Ktile dbuf, both-sides XOR swizzle, counted vmcnt, setprio.
//     GEMM1 256x256 (192 blk), GEMM2 128x256 (256 blk, perfect fill). attn/prep = r5 (proven).

#define DEV __device__ __forceinline__

typedef __attribute__((ext_vector_type(4))) float  f32x4;
typedef __attribute__((ext_vector_type(4))) short  short4v;
typedef __attribute__((ext_vector_type(8))) short  short8;
typedef __attribute__((ext_vector_type(8))) __bf16 bf16x8;

DEV short f32_to_bf16(float x) {
  union { float f; uint32_t u; } v; v.f = x;
  uint32_t r = v.u + 0x7fffu + ((v.u >> 16) & 1u);   // RNE
  return (short)(r >> 16);
}

union frag_u { short4v h[2]; bf16x8 v; short s[8]; };
DEV bf16x8 comb(short4v lo, short4v hi) { frag_u u; u.h[0] = lo; u.h[1] = hi; return u.v; }

DEV f32x4 MFMA(bf16x8 a, bf16x8 b, f32x4 c) {
  return __builtin_amdgcn_mfma_f32_16x16x32_bf16(a, b, c, 0, 0, 0);
}

typedef __attribute__((address_space(1))) void* gas1p;
typedef __attribute__((address_space(3))) void* as3p;
DEV void gld16(const void* g, void* l) {
  __builtin_amdgcn_global_load_lds((gas1p)g, (as3p)l, 16, 0, 0);
}

#define BAR()   { __builtin_amdgcn_s_barrier(); __builtin_amdgcn_sched_barrier(0); }
#define LGKM0() { asm volatile("s_waitcnt lgkmcnt(0)" ::: "memory"); __builtin_amdgcn_sched_barrier(0); }
#define VMC(n)  { asm volatile("s_waitcnt vmcnt(" #n ")" ::: "memory"); __builtin_amdgcn_sched_barrier(0); }

// ---------------- prep kernels ----------------

__global__ __launch_bounds__(256) void k_cvt_bf16(const float* __restrict__ x,
                                                  short* __restrict__ y, int n4) {
  int i = blockIdx.x * 256 + threadIdx.x;
  int stride = gridDim.x * 256;
  for (; i < n4; i += stride) {
    f32x4 v = ((const f32x4*)x)[i];
    short4v o;
    o[0] = f32_to_bf16(v[0]); o[1] = f32_to_bf16(v[1]);
    o[2] = f32_to_bf16(v[2]); o[3] = f32_to_bf16(v[3]);
    ((short4v*)y)[i] = o;
  }
}

// dst[c][r] = bf16(src[r][c]);  src is [R][C] f32
__global__ __launch_bounds__(256) void k_transpose_bf16(const float* __restrict__ src,
                                                        short* __restrict__ dst, int R, int C) {
  __shared__ float tile[32][33];
  const int c0 = blockIdx.x * 32, r0 = blockIdx.y * 32;
  const int tx = threadIdx.x & 31, ty = threadIdx.x >> 5;
  #pragma unroll
  for (int i = ty; i < 32; i += 8) tile[i][tx] = src[(long)(r0 + i) * C + c0 + tx];
  __syncthreads();
  #pragma unroll
  for (int i = ty; i < 32; i += 8) dst[(long)(c0 + i) * R + r0 + tx] = f32_to_bf16(tile[tx][i]);
}

__global__ void k_rope_tab(float* __restrict__ ct, float* __restrict__ st) {
  const int s = blockIdx.x, j = threadIdx.x;   // grid 2048 x 64
  float inv = powf(10000.0f, -(float)j * (1.0f / 64.0f));
  float a = (float)s * inv;
  ct[s * 64 + j] = cosf(a);
  st[s * 64 + j] = sinf(a);
}

// From C1[s][6144] f32: rope+pack Q->Qh[32][2048][128], K->Kh[8][2048][128], V->Vt[8][128][2048]
__global__ __launch_bounds__(256) void k_rope_pack(const float* __restrict__ C1,
                                                   const float* __restrict__ ct,
                                                   const float* __restrict__ st,
                                                   short* __restrict__ Qh,
                                                   short* __restrict__ Kh,
                                                   short* __restrict__ Vt) {
  const int s = blockIdx.x, t = threadIdx.x;
  const float* row = C1 + (long)s * 6144;
  const float* cr = ct + s * 64;
  const float* sr = st + s * 64;
  for (int i = t; i < 2048; i += 256) {       // Q
    int hh = i >> 6, j = i & 63;
    float c = cr[j], sn = sr[j];
    float x0 = row[hh * 128 + j], x1 = row[hh * 128 + j + 64];
    long o = ((long)hh * 2048 + s) * 128 + j;
    Qh[o]      = f32_to_bf16(x0 * c - x1 * sn);
    Qh[o + 64] = f32_to_bf16(x1 * c + x0 * sn);
  }
  for (int i = t; i < 512; i += 256) {        // K
    int hh = i >> 6, j = i & 63;
    float c = cr[j], sn = sr[j];
    float x0 = row[4096 + hh * 128 + j], x1 = row[4096 + hh * 128 + j + 64];
    long o = ((long)hh * 2048 + s) * 128 + j;
    Kh[o]      = f32_to_bf16(x0 * c - x1 * sn);
    Kh[o + 64] = f32_to_bf16(x1 * c + x0 * sn);
  }
  for (int i = t; i < 1024; i += 256) {       // V transpose
    int hh = i >> 7, d = i & 127;
    Vt[((long)hh * 128 + d) * 2048 + s] = f32_to_bf16(row[5120 + i]);
  }
}

// ---------------- 8-phase GEMM: C[M][N] = A[M][K] * B^T  (Bt is [N][K] bf16) ----------------
// BM = MR*32 (MR=8 -> 256, MR=4 -> 128), BN = 256, BK = 64. 8 waves = 2M x 4N.
// LDS: 2 K-tile buffers, rows of 128B = 8 slots of 16B, slot XOR (row&7) both sides.

template<int MR, int OUT_BF16>
__global__ __launch_bounds__(512, 2) void k_gemm8p(const short* __restrict__ A,
                                                   const short* __restrict__ Bt,
                                                   void* __restrict__ Cp,
                                                   int M, int N, int K) {
  constexpr int BM = MR * 32;
  __shared__ short As[2][BM][64];
  __shared__ short Bs[2][256][64];
  const int tid = threadIdx.x;
  const int lane = tid & 63;
  const int w = tid >> 6;              // 0..7
  const int wm = w >> 2, wn = w & 3;
  const int wr = wm * (MR * 16);
  const int wc = wn * 64;
  const int g = lane >> 4, r16 = lane & 15;
  const long m0 = (long)blockIdx.y * BM;
  const long n0 = (long)blockIdx.x * 256;
  const int l8 = lane >> 3, l7 = lane & 7;
  const int sslot = l7 ^ l8;           // pre-swizzled source slot (row&7 == l8 at 8-row-aligned bases)

  f32x4 acc[MR][4] = {};
  const int NT = K >> 6;               // K-tiles of 64 (even for K=4096)
  const int NI = NT >> 1;

  // staging: linear LDS dest (wave-uniform base + lane*16), XOR'd global source slot
  auto stageA = [&](int half, int kt, int buf) {
    #pragma unroll
    for (int L = 0; L < MR / 4; ++L) {
      const int rb = half * (BM / 2) + (w * (MR / 4) + L) * 8;
      gld16(A + (m0 + rb + l8) * (long)K + kt * 64 + sslot * 8, (char*)&As[buf][rb][0]);
    }
  };
  auto stageB = [&](int half, int kt, int buf) {
    #pragma unroll
    for (int L = 0; L < 2; ++L) {
      const int rb = half * 128 + (w * 2 + L) * 8;
      gld16(Bt + (n0 + rb + l8) * (long)K + kt * 64 + sslot * 8, (char*)&Bs[buf][rb][0]);
    }
  };
  // swizzled fragment reads (2-way bank aliasing = free)
  auto ldA = [&](int m, int kk, int buf) -> bf16x8 {
    const int row = wr + m * 16 + r16;
    const int slot = ((kk << 2) | g) ^ (r16 & 7);
    return *(const bf16x8*)((const char*)&As[buf][0][0] + row * 128 + slot * 16);
  };
  auto ldB = [&](int n, int kk, int buf) -> bf16x8 {
    const int row = wc + n * 16 + r16;
    const int slot = ((kk << 2) | g) ^ (r16 & 7);
    return *(const bf16x8*)((const char*)&Bs[buf][0][0] + row * 128 + slot * 16);
  };

  bf16x8 af[2][MR / 2][2];   // [mh][m][kk]
  bf16x8 bf[2][2][2];        // [nh][n][kk]

  #define LDA_H(mh, buf) { _Pragma("unroll") for (int m = 0; m < MR/2; ++m) \
                           _Pragma("unroll") for (int kk = 0; kk < 2; ++kk) \
                             af[mh][m][kk] = ldA((mh) * (MR/2) + m, kk, (buf)); }
  #define LDB_H(nh, buf) { _Pragma("unroll") for (int n = 0; n < 2; ++n)    \
                           _Pragma("unroll") for (int kk = 0; kk < 2; ++kk) \
                             bf[nh][n][kk] = ldB((nh) * 2 + n, kk, (buf)); }
  #define QUAD(mh, nh) { __builtin_amdgcn_s_setprio(1);                      \
    _Pragma("unroll") for (int m = 0; m < MR/2; ++m)                         \
    _Pragma("unroll") for (int n = 0; n < 2; ++n)                            \
    _Pragma("unroll") for (int kk = 0; kk < 2; ++kk)                         \
      acc[(mh)*(MR/2)+m][(nh)*2+n] =                                         \
        MFMA(af[mh][m][kk], bf[nh][n][kk], acc[(mh)*(MR/2)+m][(nh)*2+n]);    \
    __builtin_amdgcn_s_setprio(0); }
  #define VMAL() { if constexpr (MR == 8) VMC(4) else VMC(2) }

  // prologue: K-tile0 (buf0) fully, A of K-tile1 (buf1); wait own loads to K-tile0, barrier
  stageA(0, 0, 0); stageA(1, 0, 0); stageB(0, 0, 0); stageB(1, 0, 0);
  stageA(0, 1, 1); stageA(1, 1, 1);
  VMAL();
  BAR();

  for (int i = 0; i < NI; ++i) {
    const int kt0 = 2 * i, kt1 = 2 * i + 1;
    const bool more = (i + 1 < NI);
    // ---- K-tile kt0 from buf0 ----
    // p0
    LDA_H(0, 0); LDB_H(0, 0);
    stageB(0, kt1, 1);
    BAR(); LGKM0(); QUAD(0, 0); BAR();
    // p1
    LDA_H(1, 0);
    stageB(1, kt1, 1);
    BAR(); LGKM0(); QUAD(1, 0); BAR();
    // p2
    LDB_H(1, 0);
    if (more) stageA(0, kt0 + 2, 0);
    BAR(); LGKM0(); QUAD(0, 1); BAR();
    // p3
    if (more) stageA(1, kt0 + 2, 0);
    QUAD(1, 1);
    if (more) { VMAL(); } else { VMC(0); }
    BAR();
    // ---- K-tile kt1 from buf1 ----
    // p4
    LDA_H(0, 1); LDB_H(0, 1);
    if (more) stageB(0, kt0 + 2, 0);
    BAR(); LGKM0(); QUAD(0, 0); BAR();
    // p5
    LDA_H(1, 1);
    if (more) stageB(1, kt0 + 2, 0);
    BAR(); LGKM0(); QUAD(1, 0); BAR();
    // p6
    LDB_H(1, 1);
    if (more) stageA(0, kt1 + 2, 1);
    BAR(); LGKM0(); QUAD(0, 1); BAR();
    // p7
    if (more) stageA(1, kt1 + 2, 1);
    QUAD(1, 1);
    if (more) { VMAL(); } else { VMC(0); }
    BAR();
  }
  #undef LDA_H
  #undef LDB_H
  #undef QUAD
  #undef VMAL

  #pragma unroll
  for (int m = 0; m < MR; ++m) {
    #pragma unroll
    for (int n = 0; n < 4; ++n) {
      const long col = n0 + wc + n * 16 + r16;
      #pragma unroll
      for (int j = 0; j < 4; ++j) {
        const long row = m0 + wr + m * 16 + g * 4 + j;   // C/D: col=lane&15, row=(lane>>4)*4+reg
        if (OUT_BF16) ((short*)Cp)[row * N + col] = f32_to_bf16(acc[m][n][j]);
        else          ((float*)Cp)[row * N + col] = acc[m][n][j];
      }
    }
  }
}

// ---------------- flash attention (causal, GQA 4:1), swapped-QK^T (r5, proven) ----------------

__global__ __launch_bounds__(256) void k_attn(const short* __restrict__ Qh,
                                              const short* __restrict__ Kh,
                                              const short* __restrict__ Vt,
                                              short* __restrict__ O) {
  __shared__ short Kl[64][136];
  __shared__ short Vl[128][72];
  const int h = blockIdx.x, qt = blockIdx.y, hk = h >> 2;
  const int tid = threadIdx.x, lane = tid & 63, w = tid >> 6;
  const int g = lane >> 4, r16 = lane & 15;
  const int q0 = qt * 64 + w * 16;
  const int q_glob = q0 + r16;

  bf16x8 qf[4];
  {
    const short* qb = Qh + ((long)h * 2048 + q0 + r16) * 128;
    #pragma unroll
    for (int c = 0; c < 4; ++c) {
      short4v lo = *(const short4v*)(qb + 32 * c + 4 * g);
      short4v hi = *(const short4v*)(qb + 32 * c + 16 + 4 * g);
      qf[c] = comb(lo, hi);
    }
  }
  const short* Kg = Kh + (long)hk * (2048 * 128);
  const short* Vg = Vt + (long)hk * (128 * 2048);

  f32x4 accO[8] = {};
  float mrun = -1e30f, lrun = 0.0f;

  short8 kpre[4], vpre[4];
  #pragma unroll
  for (int j = 0; j < 4; ++j) {
    const int n = tid + j * 256;
    kpre[j] = *(const short8*)(Kg + ((long)(n >> 4)) * 128 + (n & 15) * 8);
    vpre[j] = *(const short8*)(Vg + (long)(n >> 3) * 2048 + (n & 7) * 8);
  }

  for (int kt = 0; kt <= qt; ++kt) {
    #pragma unroll
    for (int j = 0; j < 4; ++j) {
      const int n = tid + j * 256;
      *(short8*)(&Kl[n >> 4][(n & 15) * 8]) = kpre[j];
      *(short8*)(&Vl[n >> 3][(n & 7) * 8]) = vpre[j];
    }
    __syncthreads();

    if (kt < qt) {
      const long koff = (long)(kt + 1) * 64;
      #pragma unroll
      for (int j = 0; j < 4; ++j) {
        const int n = tid + j * 256;
        kpre[j] = *(const short8*)(Kg + (koff + (n >> 4)) * 128 + (n & 15) * 8);
        vpre[j] = *(const short8*)(Vg + (long)(n >> 3) * 2048 + koff + (n & 7) * 8);
      }
    }

    f32x4 accS[4] = {};
    __builtin_amdgcn_s_setprio(1);
    #pragma unroll
    for (int kvf = 0; kvf < 4; ++kvf) {
      const short* kr = &Kl[kvf * 16 + r16][0];
      #pragma unroll
      for (int c = 0; c < 4; ++c) {
        short4v lo = *(const short4v*)(kr + 32 * c + 4 * g);
        short4v hi = *(const short4v*)(kr + 32 * c + 16 + 4 * g);
        accS[kvf] = MFMA(comb(lo, hi), qf[c], accS[kvf]);
      }
    }
    __builtin_amdgcn_s_setprio(0);

    float sc[4][4];
    float mt = -1e30f;
    #pragma unroll
    for (int kvf = 0; kvf < 4; ++kvf)
      #pragma unroll
      for (int r = 0; r < 4; ++r) {
        float s = accS[kvf][r] * 0.08838834764831845f;
        const int kvg = kt * 64 + kvf * 16 + g * 4 + r;
        if (kvg > q_glob) s = -1e30f;
        sc[kvf][r] = s;
        mt = fmaxf(mt, s);
      }
    mt = fmaxf(mt, __shfl_xor(mt, 16));
    mt = fmaxf(mt, __shfl_xor(mt, 32));
    const float mnew = fmaxf(mrun, mt);
    const float scale = __expf(mrun - mnew);
    float ps = 0.0f;
    #pragma unroll
    for (int kvf = 0; kvf < 4; ++kvf)
      #pragma unroll
      for (int r = 0; r < 4; ++r) {
        float p = __expf(sc[kvf][r] - mnew);
        sc[kvf][r] = p;
        ps += p;
      }
    ps += __shfl_xor(ps, 16);
    ps += __shfl_xor(ps, 32);
    lrun = lrun * scale + ps;
    mrun = mnew;

    frag_u p0, p1;
    #pragma unroll
    for (int e = 0; e < 4; ++e) {
      p0.s[e]     = f32_to_bf16(sc[0][e]);
      p0.s[e + 4] = f32_to_bf16(sc[1][e]);
      p1.s[e]     = f32_to_bf16(sc[2][e]);
      p1.s[e + 4] = f32_to_bf16(sc[3][e]);
    }
    #pragma unroll
    for (int df = 0; df < 8; ++df)
      #pragma unroll
      for (int j = 0; j < 4; ++j) accO[df][j] *= scale;

    __builtin_amdgcn_s_setprio(1);
    #pragma unroll
    for (int df = 0; df < 8; ++df) {
      const short* vr = &Vl[df * 16 + r16][0];
      short4v a0 = *(const short4v*)(vr + 4 * g);
      short4v a1 = *(const short4v*)(vr + 16 + 4 * g);
      short4v a2 = *(const short4v*)(vr + 32 + 4 * g);
      short4v a3 = *(const short4v*)(vr + 48 + 4 * g);
      accO[df] = MFMA(comb(a0, a1), p0.v, accO[df]);
      accO[df] = MFMA(comb(a2, a3), p1.v, accO[df]);
    }
    __builtin_amdgcn_s_setprio(0);
    __syncthreads();
  }

  const float invl = 1.0f / lrun;
  #pragma unroll
  for (int df = 0; df < 8; ++df)
    #pragma unroll
    for (int j = 0; j < 4; ++j) {
      const int d = df * 16 + g * 4 + j;
      O[(long)q_glob * 4096 + h * 128 + d] = f32_to_bf16(accO[df][j] * invl);
    }
}

// ---------------- launch ----------------

extern "C" void kernel_launch(void* const* d_in, const int* in_sizes, int n_in,
                              void* d_out, int out_size, void* d_ws, size_t ws_size,
                              hipStream_t stream) {
  const float* hs   = (const float*)d_in[0];
  const float* wqkv = (const float*)d_in[1];
  const float* wo   = (const float*)d_in[2];

  const size_t OFF_HSB = 0;                 // 16,777,216  (aliased by Qh later)
  const size_t OFF_W1T = 16777216;          // 50,331,648
  const size_t OFF_WOT = 67108864;          // 33,554,432
  const size_t OFF_C1  = 100663296;         // 50,331,648  (first 16.7MB aliased by attn-out)
  const size_t OFF_CT  = 150994944;         //    524,288
  const size_t OFF_ST  = 151519232;         //    524,288
  const size_t OFF_KH  = 152043520;         //  4,194,304
  const size_t OFF_VT  = 156237824;         //  4,194,304  -> end 160,432,128
  if (ws_size < 160432128u) return;

  char* ws = (char*)d_ws;
  short* hsb = (short*)(ws + OFF_HSB);
  short* W1T = (short*)(ws + OFF_W1T);
  short* WoT = (short*)(ws + OFF_WOT);
  float* C1  = (float*)(ws + OFF_C1);
  float* ct  = (float*)(ws + OFF_CT);
  float* st  = (float*)(ws + OFF_ST);
  short* Kh  = (short*)(ws + OFF_KH);
  short* Vt  = (short*)(ws + OFF_VT);
  short* Qh  = hsb;                     // reuse: hsb dead after gemm1
  short* AO  = (short*)(ws + OFF_C1);   // reuse: C1 dead after rope_pack

  k_cvt_bf16<<<2048, 256, 0, stream>>>(hs, hsb, 2048 * 4096 / 4);
  k_transpose_bf16<<<dim3(6144 / 32, 4096 / 32), 256, 0, stream>>>(wqkv, W1T, 4096, 6144);
  k_transpose_bf16<<<dim3(4096 / 32, 4096 / 32), 256, 0, stream>>>(wo, WoT, 4096, 4096);
  k_rope_tab<<<2048, 64, 0, stream>>>(ct, st);
  k_gemm8p<8, 0><<<dim3(24, 8), 512, 0, stream>>>(hsb, W1T, (void*)C1, 2048, 6144, 4096);
  k_rope_pack<<<2048, 256, 0, stream>>>(C1, ct, st, Qh, Kh, Vt);
  k_attn<<<dim3(32, 32), 256, 0, stream>>>(Qh, Kh, Vt, AO);   // x=h, y=qt
  k_gemm8p<4, 0><<<dim3(16, 16), 512, 0, stream>>>(AO, WoT, (void*)d_out, 2048, 4096, 4096);
}

// Round 8
// 422.884 us; speedup vs baseline: 1.2948x; 1.0630x over previous
//
#include <hip/hip_runtime.h>
#include <cstdint>
#include <cstddef>

// Problem: B=1, S=2048, H=4096, NH=32, NKV=8, D=128, rope theta 1e4, causal GQA attn.
// Inputs f32: hidden[2048][4096], w_qkv[4096][6144], w_o[4096][4096], mask(tril, unused), pos(arange, unused)
// Output f32 [2048][4096]
// R8: GEMMs unpinned (no asm, no sched_barrier — m141 lesson): 256x256/BK=64, 2-buf,
//     stage-early gld16, XOR swizzle (proven, 0 conflicts), quad-ordered frag loads,
//     compiler-scheduled lgkm interleave, __syncthreads at tile boundary only.

#define DEV __device__ __forceinline__

typedef __attribute__((ext_vector_type(4))) float  f32x4;
typedef __attribute__((ext_vector_type(4))) short  short4v;
typedef __attribute__((ext_vector_type(8))) short  short8;
typedef __attribute__((ext_vector_type(8))) __bf16 bf16x8;

DEV short f32_to_bf16(float x) {
  union { float f; uint32_t u; } v; v.f = x;
  uint32_t r = v.u + 0x7fffu + ((v.u >> 16) & 1u);   // RNE
  return (short)(r >> 16);
}

union frag_u { short4v h[2]; bf16x8 v; short s[8]; };
DEV bf16x8 comb(short4v lo, short4v hi) { frag_u u; u.h[0] = lo; u.h[1] = hi; return u.v; }

DEV f32x4 MFMA(bf16x8 a, bf16x8 b, f32x4 c) {
  return __builtin_amdgcn_mfma_f32_16x16x32_bf16(a, b, c, 0, 0, 0);
}

typedef __attribute__((address_space(1))) void* gas1p;
typedef __attribute__((address_space(3))) void* as3p;
DEV void gld16(const void* g, void* l) {
  __builtin_amdgcn_global_load_lds((gas1p)g, (as3p)l, 16, 0, 0);
}

// ---------------- prep kernels ----------------

__global__ __launch_bounds__(256) void k_cvt_bf16(const float* __restrict__ x,
                                                  short* __restrict__ y, int n4) {
  int i = blockIdx.x * 256 + threadIdx.x;
  int stride = gridDim.x * 256;
  for (; i < n4; i += stride) {
    f32x4 v = ((const f32x4*)x)[i];
    short4v o;
    o[0] = f32_to_bf16(v[0]); o[1] = f32_to_bf16(v[1]);
    o[2] = f32_to_bf16(v[2]); o[3] = f32_to_bf16(v[3]);
    ((short4v*)y)[i] = o;
  }
}

// dst[c][r] = bf16(src[r][c]);  src is [R][C] f32
__global__ __launch_bounds__(256) void k_transpose_bf16(const float* __restrict__ src,
                                                        short* __restrict__ dst, int R, int C) {
  __shared__ float tile[32][33];
  const int c0 = blockIdx.x * 32, r0 = blockIdx.y * 32;
  const int tx = threadIdx.x & 31, ty = threadIdx.x >> 5;
  #pragma unroll
  for (int i = ty; i < 32; i += 8) tile[i][tx] = src[(long)(r0 + i) * C + c0 + tx];
  __syncthreads();
  #pragma unroll
  for (int i = ty; i < 32; i += 8) dst[(long)(c0 + i) * R + r0 + tx] = f32_to_bf16(tile[tx][i]);
}

__global__ void k_rope_tab(float* __restrict__ ct, float* __restrict__ st) {
  const int s = blockIdx.x, j = threadIdx.x;   // grid 2048 x 64
  float inv = powf(10000.0f, -(float)j * (1.0f / 64.0f));
  float a = (float)s * inv;
  ct[s * 64 + j] = cosf(a);
  st[s * 64 + j] = sinf(a);
}

// From C1[s][6144] f32: rope+pack Q->Qh[32][2048][128], K->Kh[8][2048][128], V->Vt[8][128][2048]
__global__ __launch_bounds__(256) void k_rope_pack(const float* __restrict__ C1,
                                                   const float* __restrict__ ct,
                                                   const float* __restrict__ st,
                                                   short* __restrict__ Qh,
                                                   short* __restrict__ Kh,
                                                   short* __restrict__ Vt) {
  const int s = blockIdx.x, t = threadIdx.x;
  const float* row = C1 + (long)s * 6144;
  const float* cr = ct + s * 64;
  const float* sr = st + s * 64;
  for (int i = t; i < 2048; i += 256) {       // Q
    int hh = i >> 6, j = i & 63;
    float c = cr[j], sn = sr[j];
    float x0 = row[hh * 128 + j], x1 = row[hh * 128 + j + 64];
    long o = ((long)hh * 2048 + s) * 128 + j;
    Qh[o]      = f32_to_bf16(x0 * c - x1 * sn);
    Qh[o + 64] = f32_to_bf16(x1 * c + x0 * sn);
  }
  for (int i = t; i < 512; i += 256) {        // K
    int hh = i >> 6, j = i & 63;
    float c = cr[j], sn = sr[j];
    float x0 = row[4096 + hh * 128 + j], x1 = row[4096 + hh * 128 + j + 64];
    long o = ((long)hh * 2048 + s) * 128 + j;
    Kh[o]      = f32_to_bf16(x0 * c - x1 * sn);
    Kh[o + 64] = f32_to_bf16(x1 * c + x0 * sn);
  }
  for (int i = t; i < 1024; i += 256) {       // V transpose
    int hh = i >> 7, d = i & 127;
    Vt[((long)hh * 128 + d) * 2048 + s] = f32_to_bf16(row[5120 + i]);
  }
}

// ---------------- GEMM: C[M][N] = A[M][K] * B^T  (Bt is [N][K] bf16) ----------------
// BM = MR*32, BN = 256, BK = 64. 8 waves = 2M x 4N. 2 K-tile LDS buffers (XOR-swizzled slots).
// No asm, no sched_barrier: stage-early + plain quad-ordered code; compiler schedules lgkm.

template<int MR, int OUT_BF16>
__global__ __launch_bounds__(512, 2) void k_gemm8p(const short* __restrict__ A,
                                                   const short* __restrict__ Bt,
                                                   void* __restrict__ Cp,
                                                   int M, int N, int K) {
  constexpr int BM = MR * 32;
  __shared__ short As[2][BM][64];
  __shared__ short Bs[2][256][64];
  const int tid = threadIdx.x;
  const int lane = tid & 63;
  const int w = tid >> 6;              // 0..7
  const int wm = w >> 2, wn = w & 3;
  const int wr = wm * (MR * 16);
  const int wc = wn * 64;
  const int g = lane >> 4, r16 = lane & 15;
  const long m0 = (long)blockIdx.y * BM;
  const long n0 = (long)blockIdx.x * 256;
  const int l8 = lane >> 3, l7 = lane & 7;
  const int sslot = l7 ^ l8;           // pre-swizzled global source slot (LDS dest stays linear)

  f32x4 acc[MR][4] = {};
  const int NT = K >> 6;

  auto stageTile = [&](int kt, int buf) {
    #pragma unroll
    for (int L = 0; L < MR / 2; ++L) {
      const int rb = (w * (MR / 2) + L) * 8;
      gld16(A + (m0 + rb + l8) * (long)K + kt * 64 + sslot * 8, (char*)&As[buf][rb][0]);
    }
    #pragma unroll
    for (int L = 0; L < 4; ++L) {
      const int rb = (w * 4 + L) * 8;
      gld16(Bt + (n0 + rb + l8) * (long)K + kt * 64 + sslot * 8, (char*)&Bs[buf][rb][0]);
    }
  };
  // swizzled fragment reads: LDS[row][slot] holds global[row][slot ^ (row&7)]
  auto ldA = [&](int m, int kk, int buf) -> bf16x8 {
    const int row = wr + m * 16 + r16;
    const int slot = ((kk << 2) | g) ^ (r16 & 7);
    return *(const bf16x8*)((const char*)&As[buf][0][0] + row * 128 + slot * 16);
  };
  auto ldB = [&](int n, int kk, int buf) -> bf16x8 {
    const int row = wc + n * 16 + r16;
    const int slot = ((kk << 2) | g) ^ (r16 & 7);
    return *(const bf16x8*)((const char*)&Bs[buf][0][0] + row * 128 + slot * 16);
  };

  // prologue: tile 0 into buf 0
  stageTile(0, 0);
  __syncthreads();

  for (int t = 0; t < NT; ++t) {
    const int buf = t & 1;
    if (t + 1 < NT) stageTile(t + 1, buf ^ 1);   // issued early; lands by boundary sync

    bf16x8 a[MR / 2][2], b[2][2];
    #pragma unroll
    for (int mh = 0; mh < 2; ++mh) {
      // load A-half once, reuse across both B-halves (B reloaded: caps VGPR for 2 waves/SIMD)
      #pragma unroll
      for (int m = 0; m < MR / 2; ++m)
        #pragma unroll
        for (int kk = 0; kk < 2; ++kk) a[m][kk] = ldA(mh * (MR / 2) + m, kk, buf);
      #pragma unroll
      for (int nh = 0; nh < 2; ++nh) {
        #pragma unroll
        for (int n = 0; n < 2; ++n)
          #pragma unroll
          for (int kk = 0; kk < 2; ++kk) b[n][kk] = ldB(nh * 2 + n, kk, buf);
        #pragma unroll
        for (int m = 0; m < MR / 2; ++m)
          #pragma unroll
          for (int n = 0; n < 2; ++n)
            #pragma unroll
            for (int kk = 0; kk < 2; ++kk)
              acc[mh * (MR / 2) + m][nh * 2 + n] =
                MFMA(a[m][kk], b[n][kk], acc[mh * (MR / 2) + m][nh * 2 + n]);
      }
    }
    __syncthreads();   // drains vmcnt (stage t+1 landed) + lgkm; protects buf reuse
  }

  #pragma unroll
  for (int m = 0; m < MR; ++m) {
    #pragma unroll
    for (int n = 0; n < 4; ++n) {
      const long col = n0 + wc + n * 16 + r16;
      #pragma unroll
      for (int j = 0; j < 4; ++j) {
        const long row = m0 + wr + m * 16 + g * 4 + j;   // C/D: col=lane&15, row=(lane>>4)*4+reg
        if (OUT_BF16) ((short*)Cp)[row * N + col] = f32_to_bf16(acc[m][n][j]);
        else          ((float*)Cp)[row * N + col] = acc[m][n][j];
      }
    }
  }
}

// ---------------- flash attention (causal, GQA 4:1), swapped-QK^T (r5/r7, proven) ----------------

__global__ __launch_bounds__(256) void k_attn(const short* __restrict__ Qh,
                                              const short* __restrict__ Kh,
                                              const short* __restrict__ Vt,
                                              short* __restrict__ O) {
  __shared__ short Kl[64][136];
  __shared__ short Vl[128][72];
  const int h = blockIdx.x, qt = blockIdx.y, hk = h >> 2;
  const int tid = threadIdx.x, lane = tid & 63, w = tid >> 6;
  const int g = lane >> 4, r16 = lane & 15;
  const int q0 = qt * 64 + w * 16;
  const int q_glob = q0 + r16;

  bf16x8 qf[4];
  {
    const short* qb = Qh + ((long)h * 2048 + q0 + r16) * 128;
    #pragma unroll
    for (int c = 0; c < 4; ++c) {
      short4v lo = *(const short4v*)(qb + 32 * c + 4 * g);
      short4v hi = *(const short4v*)(qb + 32 * c + 16 + 4 * g);
      qf[c] = comb(lo, hi);
    }
  }
  const short* Kg = Kh + (long)hk * (2048 * 128);
  const short* Vg = Vt + (long)hk * (128 * 2048);

  f32x4 accO[8] = {};
  float mrun = -1e30f, lrun = 0.0f;

  short8 kpre[4], vpre[4];
  #pragma unroll
  for (int j = 0; j < 4; ++j) {
    const int n = tid + j * 256;
    kpre[j] = *(const short8*)(Kg + ((long)(n >> 4)) * 128 + (n & 15) * 8);
    vpre[j] = *(const short8*)(Vg + (long)(n >> 3) * 2048 + (n & 7) * 8);
  }

  for (int kt = 0; kt <= qt; ++kt) {
    #pragma unroll
    for (int j = 0; j < 4; ++j) {
      const int n = tid + j * 256;
      *(short8*)(&Kl[n >> 4][(n & 15) * 8]) = kpre[j];
      *(short8*)(&Vl[n >> 3][(n & 7) * 8]) = vpre[j];
    }
    __syncthreads();

    if (kt < qt) {
      const long koff = (long)(kt + 1) * 64;
      #pragma unroll
      for (int j = 0; j < 4; ++j) {
        const int n = tid + j * 256;
        kpre[j] = *(const short8*)(Kg + (koff + (n >> 4)) * 128 + (n & 15) * 8);
        vpre[j] = *(const short8*)(Vg + (long)(n >> 3) * 2048 + koff + (n & 7) * 8);
      }
    }

    f32x4 accS[4] = {};
    __builtin_amdgcn_s_setprio(1);
    #pragma unroll
    for (int kvf = 0; kvf < 4; ++kvf) {
      const short* kr = &Kl[kvf * 16 + r16][0];
      #pragma unroll
      for (int c = 0; c < 4; ++c) {
        short4v lo = *(const short4v*)(kr + 32 * c + 4 * g);
        short4v hi = *(const short4v*)(kr + 32 * c + 16 + 4 * g);
        accS[kvf] = MFMA(comb(lo, hi), qf[c], accS[kvf]);
      }
    }
    __builtin_amdgcn_s_setprio(0);

    float sc[4][4];
    float mt = -1e30f;
    #pragma unroll
    for (int kvf = 0; kvf < 4; ++kvf)
      #pragma unroll
      for (int r = 0; r < 4; ++r) {
        float s = accS[kvf][r] * 0.08838834764831845f;
        const int kvg = kt * 64 + kvf * 16 + g * 4 + r;
        if (kvg > q_glob) s = -1e30f;
        sc[kvf][r] = s;
        mt = fmaxf(mt, s);
      }
    mt = fmaxf(mt, __shfl_xor(mt, 16));
    mt = fmaxf(mt, __shfl_xor(mt, 32));
    const float mnew = fmaxf(mrun, mt);
    const float scale = __expf(mrun - mnew);
    float ps = 0.0f;
    #pragma unroll
    for (int kvf = 0; kvf < 4; ++kvf)
      #pragma unroll
      for (int r = 0; r < 4; ++r) {
        float p = __expf(sc[kvf][r] - mnew);
        sc[kvf][r] = p;
        ps += p;
      }
    ps += __shfl_xor(ps, 16);
    ps += __shfl_xor(ps, 32);
    lrun = lrun * scale + ps;
    mrun = mnew;

    frag_u p0, p1;
    #pragma unroll
    for (int e = 0; e < 4; ++e) {
      p0.s[e]     = f32_to_bf16(sc[0][e]);
      p0.s[e + 4] = f32_to_bf16(sc[1][e]);
      p1.s[e]     = f32_to_bf16(sc[2][e]);
      p1.s[e + 4] = f32_to_bf16(sc[3][e]);
    }
    #pragma unroll
    for (int df = 0; df < 8; ++df)
      #pragma unroll
      for (int j = 0; j < 4; ++j) accO[df][j] *= scale;

    __builtin_amdgcn_s_setprio(1);
    #pragma unroll
    for (int df = 0; df < 8; ++df) {
      const short* vr = &Vl[df * 16 + r16][0];
      short4v a0 = *(const short4v*)(vr + 4 * g);
      short4v a1 = *(const short4v*)(vr + 16 + 4 * g);
      short4v a2 = *(const short4v*)(vr + 32 + 4 * g);
      short4v a3 = *(const short4v*)(vr + 48 + 4 * g);
      accO[df] = MFMA(comb(a0, a1), p0.v, accO[df]);
      accO[df] = MFMA(comb(a2, a3), p1.v, accO[df]);
    }
    __builtin_amdgcn_s_setprio(0);
    __syncthreads();
  }

  const float invl = 1.0f / lrun;
  #pragma unroll
  for (int df = 0; df < 8; ++df)
    #pragma unroll
    for (int j = 0; j < 4; ++j) {
      const int d = df * 16 + g * 4 + j;
      O[(long)q_glob * 4096 + h * 128 + d] = f32_to_bf16(accO[df][j] * invl);
    }
}

// ---------------- launch ----------------

extern "C" void kernel_launch(void* const* d_in, const int* in_sizes, int n_in,
                              void* d_out, int out_size, void* d_ws, size_t ws_size,
                              hipStream_t stream) {
  const float* hs   = (const float*)d_in[0];
  const float* wqkv = (const float*)d_in[1];
  const float* wo   = (const float*)d_in[2];

  const size_t OFF_HSB = 0;                 // 16,777,216  (aliased by Qh later)
  const size_t OFF_W1T = 16777216;          // 50,331,648
  const size_t OFF_WOT = 67108864;          // 33,554,432
  const size_t OFF_C1  = 100663296;         // 50,331,648  (first 16.7MB aliased by attn-out)
  const size_t OFF_CT  = 150994944;         //    524,288
  const size_t OFF_ST  = 151519232;         //    524,288
  const size_t OFF_KH  = 152043520;         //  4,194,304
  const size_t OFF_VT  = 156237824;         //  4,194,304  -> end 160,432,128
  if (ws_size < 160432128u) return;

  char* ws = (char*)d_ws;
  short* hsb = (short*)(ws + OFF_HSB);
  short* W1T = (short*)(ws + OFF_W1T);
  short* WoT = (short*)(ws + OFF_WOT);
  float* C1  = (float*)(ws + OFF_C1);
  float* ct  = (float*)(ws + OFF_CT);
  float* st  = (float*)(ws + OFF_ST);
  short* Kh  = (short*)(ws + OFF_KH);
  short* Vt  = (short*)(ws + OFF_VT);
  short* Qh  = hsb;                     // reuse: hsb dead after gemm1
  short* AO  = (short*)(ws + OFF_C1);   // reuse: C1 dead after rope_pack

  k_cvt_bf16<<<2048, 256, 0, stream>>>(hs, hsb, 2048 * 4096 / 4);
  k_transpose_bf16<<<dim3(6144 / 32, 4096 / 32), 256, 0, stream>>>(wqkv, W1T, 4096, 6144);
  k_transpose_bf16<<<dim3(4096 / 32, 4096 / 32), 256, 0, stream>>>(wo, WoT, 4096, 4096);
  k_rope_tab<<<2048, 64, 0, stream>>>(ct, st);
  k_gemm8p<8, 0><<<dim3(24, 8), 512, 0, stream>>>(hsb, W1T, (void*)C1, 2048, 6144, 4096);
  k_rope_pack<<<2048, 256, 0, stream>>>(C1, ct, st, Qh, Kh, Vt);
  k_attn<<<dim3(32, 32), 256, 0, stream>>>(Qh, Kh, Vt, AO);   // x=h, y=qt
  k_gemm8p<4, 0><<<dim3(16, 16), 512, 0, stream>>>(AO, WoT, (void*)d_out, 2048, 4096, 4096);
}